// Round 2
// baseline (478.139 us; speedup 1.0000x reference)
//
#include <hip/hip_runtime.h>
#include <hip/hip_bf16.h>

#define VOCAB   65
#define SQRT_C  5.656854249492381f
#define BATCHES 65536
#define ROWS    (BATCHES * 8)
#define TABSZ   (8 * VOCAB * 32)       // 16640 floats per q/k/v table
#define PAIRS   (BATCHES / 2)          // 32768 batch-pairs (16 rows each)
#define NBLOCKS 2048
#define NWAVES  (NBLOCKS * 4)

typedef __attribute__((ext_vector_type(8))) short  short8;   // 8 bf16 = 4 VGPRs
typedef __attribute__((ext_vector_type(4))) float  float4v;  // MFMA C/D
typedef __attribute__((ext_vector_type(4))) int    intv4;    // 16B int load

__device__ __forceinline__ void wave_fence() {
    __asm__ volatile("s_waitcnt lgkmcnt(0)" ::: "memory");
}
__device__ __forceinline__ short bfbits(float f) {
    __hip_bfloat16 h = __float2bfloat16(f);
    return *reinterpret_cast<short*>(&h);
}
__device__ __forceinline__ float dot8(const float4 a0, const float4 a1,
                                      const float4 b0, const float4 b1) {
    return a0.x*b0.x + a0.y*b0.y + a0.z*b0.z + a0.w*b0.w
         + a1.x*b1.x + a1.y*b1.y + a1.z*b1.z + a1.w*b1.w;
}

// ---------------------------------------------------------------------------
// Kernel 1: precompute q/k/v tables over the 520 distinct (t, token) combos.
// tab[(t*65+tok)*32 + h*8 + d].  The faithful-bug score scale (* sqrt(C)) is
// folded into qtab so the fused kernel saves a multiply per score.
// ---------------------------------------------------------------------------
__global__ void qkv_table_kernel(const float* __restrict__ tok_emb,
                                 const float* __restrict__ pos_emb,
                                 const float* __restrict__ Wq,
                                 const float* __restrict__ Wk,
                                 const float* __restrict__ Wv,
                                 float* __restrict__ qtab,
                                 float* __restrict__ ktab,
                                 float* __restrict__ vtab) {
    int o = blockIdx.x * 256 + threadIdx.x;
    if (o >= 3 * TABSZ) return;
    int table = o / TABSZ;
    int r = o - table * TABSZ;
    int pair = r >> 5;
    int cd = r & 31;
    int t = pair / VOCAB;
    int tok = pair - t * VOCAB;
    int h = cd >> 3, d = cd & 7;
    const float* W = (table == 0) ? Wq : (table == 1) ? Wk : Wv;
    float acc = 0.f;
    #pragma unroll
    for (int c = 0; c < 32; ++c) {
        float xc = tok_emb[tok * 32 + c] + pos_emb[t * 32 + c];
        acc += xc * W[h * 256 + c * 8 + d];
    }
    if (table == 0) acc *= SQRT_C;     // faithful bug: scores * sqrt(C)
    float* tab = (table == 0) ? qtab : (table == 1) ? ktab : vtab;
    tab[r] = acc;
}

// ---------------------------------------------------------------------------
// Kernel 2: 4 independent waves per 256-block; each wave owns one batch-pair
// (16 logit rows) per iteration.
//  - K/V read per-lane straight from L2-resident tables (no LDS staging, no
//    fences, no token shuffles: 8 lanes per (b2,h) group share addresses).
//  - MLP + logits via bf16 MFMA 16x16x32 (x2 -> x3 transpose through LDS).
//  - Target logit extracted inline from Lc/L64 by predicate (no b6 gather).
//  - All loads/stores CACHED: L2 write-combines the scattered 4B logit
//    stores into full lines (nt stores caused 3.4x write + RMW-fetch
//    amplification in round 1: 763MB vs 140MB actual traffic).
// ---------------------------------------------------------------------------
__global__ __launch_bounds__(256, 7) void fused_kernel(
        const int* __restrict__ idx, const int* __restrict__ targets,
        const float* __restrict__ qtab, const float* __restrict__ ktab,
        const float* __restrict__ vtab,
        const float* __restrict__ W_mlp,
        const float* __restrict__ b_mlp,
        const float* __restrict__ W_lm,
        const float* __restrict__ b_lm,
        float* __restrict__ out_logits,
        float* __restrict__ loss_acc) {
    // per-wave x3 bf16 [row][ch], row-stride 40 shorts (80B, 16B-aligned)
    __shared__ __align__(16) unsigned short sX3[4][640];

    const int tid = threadIdx.x;
    const int w = tid >> 6, l = tid & 63;
    const int q4 = l >> 4;        // MFMA quad
    const int n  = l & 15;        // MFMA col-lane / A-row
    const int t  = l & 7, b2 = (l >> 3) & 1, h = q4;   // attention identity

    // ---- persistent B-fragments: B[k=(q4*8+j)][n] ----
    short8 wmf[2], wlf[4], wlf4;
    #pragma unroll
    for (int c = 0; c < 2; ++c)
        #pragma unroll
        for (int j = 0; j < 8; ++j)
            wmf[c][j] = bfbits(W_mlp[(q4 * 8 + j) * 32 + c * 16 + n]);
    #pragma unroll
    for (int c = 0; c < 4; ++c)
        #pragma unroll
        for (int j = 0; j < 8; ++j)
            wlf[c][j] = bfbits(W_lm[(q4 * 8 + j) * VOCAB + c * 16 + n]);
    #pragma unroll
    for (int j = 0; j < 8; ++j)
        wlf4[j] = (n == 0) ? bfbits(W_lm[(q4 * 8 + j) * VOCAB + 64]) : (short)0;
    float bmc[2], blc[4];
    #pragma unroll
    for (int c = 0; c < 2; ++c) bmc[c] = b_mlp[c * 16 + n];
    #pragma unroll
    for (int c = 0; c < 4; ++c) blc[c] = b_lm[c * 16 + n];
    const float bl64 = b_lm[64];
    const float4v zf = {0.f, 0.f, 0.f, 0.f};

    float loss_local = 0.f;

    for (int pb = blockIdx.x * 4 + w; pb < PAIRS; pb += NWAVES) {
        const int rbase = pb * 16;

        // ---- tokens / targets: per-lane vector loads (wave-broadcast lines)
        const intv4 ta = *((const intv4*)(idx + rbase + b2 * 8));
        const intv4 tb = *((const intv4*)(idx + rbase + b2 * 8) + 1);
        const int tok_t = idx[rbase + b2 * 8 + t];          // own q token
        const intv4 tg = *((const intv4*)(targets + rbase + q4 * 4));

        // ---- q row (already * sqrt(C)) ----
        const float* qp = qtab + (t * VOCAB + tok_t) * 32 + h * 8;
        const float4 q0 = *(const float4*)(qp);
        const float4 q1 = *(const float4*)(qp + 4);

        const int toks[8] = {ta[0], ta[1], ta[2], ta[3],
                             tb[0], tb[1], tb[2], tb[3]};

        // ---- scores: per-lane K reads (8 distinct addrs per instruction) --
        float sc[8], m = -1e30f;
        #pragma unroll
        for (int s = 0; s < 8; ++s) {
            const float* kp = ktab + (s * VOCAB + toks[s]) * 32 + h * 8;
            float4 k0 = *(const float4*)(kp);
            float4 k1 = *(const float4*)(kp + 4);
            float d = dot8(q0, q1, k0, k1);
            sc[s] = d;
            if (s <= t) m = fmaxf(m, d);
        }
        float p[8], sum = 0.f;
        #pragma unroll
        for (int s = 0; s < 8; ++s) {
            p[s] = (s <= t) ? __expf(sc[s] - m) : 0.f;
            sum += p[s];
        }
        float inv = 1.f / sum;

        // ---- V accumulation ----
        float o[8];
        #pragma unroll
        for (int d = 0; d < 8; ++d) o[d] = 0.f;
        #pragma unroll
        for (int s = 0; s < 8; ++s) {
            const float* vp = vtab + (s * VOCAB + toks[s]) * 32 + h * 8;
            float4 v0 = *(const float4*)(vp);
            float4 v1 = *(const float4*)(vp + 4);
            o[0] += p[s] * v0.x; o[1] += p[s] * v0.y;
            o[2] += p[s] * v0.z; o[3] += p[s] * v0.w;
            o[4] += p[s] * v1.x; o[5] += p[s] * v1.y;
            o[6] += p[s] * v1.z; o[7] += p[s] * v1.w;
        }
        short8 a2;
        #pragma unroll
        for (int d = 0; d < 8; ++d) a2[d] = bfbits(o[d] * inv);

        // ---- MLP: x3 = relu(x2 @ W_mlp + b), 2 MFMAs ----
        float4v d0 = __builtin_amdgcn_mfma_f32_16x16x32_bf16(a2, wmf[0], zf, 0, 0, 0);
        float4v d1 = __builtin_amdgcn_mfma_f32_16x16x32_bf16(a2, wmf[1], zf, 0, 0, 0);
        #pragma unroll
        for (int i = 0; i < 4; ++i) {
            int row = q4 * 4 + i;
            sX3[w][row * 40 + n]      = (unsigned short)bfbits(fmaxf(d0[i] + bmc[0], 0.f));
            sX3[w][row * 40 + 16 + n] = (unsigned short)bfbits(fmaxf(d1[i] + bmc[1], 0.f));
        }
        wave_fence();
        // C->A transpose via LDS: one b128 read
        short8 a3 = *(const short8*)(&sX3[w][n * 40 + q4 * 8]);

        // ---- logits: 5 MFMAs (cols 0..63 + padded col-64 fragment) ----
        float4v Lc[4];
        #pragma unroll
        for (int c = 0; c < 4; ++c)
            Lc[c] = __builtin_amdgcn_mfma_f32_16x16x32_bf16(a3, wlf[c], zf, 0, 0, 0);
        float4v L64 = __builtin_amdgcn_mfma_f32_16x16x32_bf16(a3, wlf4, zf, 0, 0, 0);

        // ---- bias + store + sum-exp + inline target pick ----
        float part[4] = {0.f, 0.f, 0.f, 0.f};
        #pragma unroll
        for (int c = 0; c < 4; ++c) {
            #pragma unroll
            for (int i = 0; i < 4; ++i) {
                float Lv = Lc[c][i] + blc[c];
                out_logits[(size_t)(rbase + q4 * 4 + i) * VOCAB + c * 16 + n] = Lv;
                part[i] += __expf(Lv);
                if (c * 16 + n == tg[i]) loss_local -= Lv;   // exactly 1 lane/row
            }
        }
        if (n == 0) {
            #pragma unroll
            for (int i = 0; i < 4; ++i) {
                float Lv = L64[i] + bl64;
                out_logits[(size_t)(rbase + q4 * 4 + i) * VOCAB + 64] = Lv;
                part[i] += __expf(Lv);
                if (tg[i] == 64) loss_local -= Lv;
            }
        }
        #pragma unroll
        for (int off = 1; off < 16; off <<= 1) {
            #pragma unroll
            for (int i = 0; i < 4; ++i) part[i] += __shfl_xor(part[i], off);
        }
        if (n == 0)
            loss_local += __logf(part[0]) + __logf(part[1])
                        + __logf(part[2]) + __logf(part[3]);
    }

    #pragma unroll
    for (int off = 1; off < 64; off <<= 1) loss_local += __shfl_xor(loss_local, off);
    if (l == 0) atomicAdd(loss_acc, loss_local);
}

__global__ void finalize_loss(const float* __restrict__ acc,
                              float* __restrict__ out) {
    out[0] = acc[0] * (1.f / (float)ROWS);
}

extern "C" void kernel_launch(void* const* d_in, const int* in_sizes, int n_in,
                              void* d_out, int out_size, void* d_ws, size_t ws_size,
                              hipStream_t stream) {
    const int* idx        = (const int*)d_in[0];
    const int* targets    = (const int*)d_in[1];
    const float* tok_emb  = (const float*)d_in[2];
    const float* pos_emb  = (const float*)d_in[3];
    const float* Wq       = (const float*)d_in[4];
    const float* Wk       = (const float*)d_in[5];
    const float* Wv       = (const float*)d_in[6];
    const float* W_mlp    = (const float*)d_in[7];
    const float* b_mlp    = (const float*)d_in[8];
    const float* W_lm     = (const float*)d_in[9];
    const float* b_lm     = (const float*)d_in[10];
    float* out            = (float*)d_out;

    float* ws       = (float*)d_ws;
    float* loss_ptr = ws;
    float* qtab     = ws + 16;
    float* ktab     = qtab + TABSZ;
    float* vtab     = ktab + TABSZ;

    hipMemsetAsync(loss_ptr, 0, sizeof(float), stream);

    qkv_table_kernel<<<(3 * TABSZ + 255) / 256, 256, 0, stream>>>(
        tok_emb, pos_emb, Wq, Wk, Wv, qtab, ktab, vtab);

    fused_kernel<<<NBLOCKS, 256, 0, stream>>>(
        idx, targets, qtab, ktab, vtab, W_mlp, b_mlp, W_lm, b_lm, out, loss_ptr);

    finalize_loss<<<1, 1, 0, stream>>>(loss_ptr, out + (size_t)ROWS * VOCAB);
}

// Round 3
// 462.824 us; speedup vs baseline: 1.0331x; 1.0331x over previous
//
#include <hip/hip_runtime.h>
#include <hip/hip_bf16.h>

#define VOCAB   65
#define SQRT_C  5.656854249492381f
#define BATCHES 65536
#define ROWS    (BATCHES * 8)
#define TABSZ   (8 * VOCAB * 32)       // 16640 floats per q/k/v table
#define PAIRS   (BATCHES / 2)          // 32768 batch-pairs (16 rows each)
#define NBLOCKS 2048
#define NWAVES  (NBLOCKS * 4)

typedef __attribute__((ext_vector_type(8))) short  short8;   // 8 bf16 = 4 VGPRs
typedef __attribute__((ext_vector_type(4))) float  float4v;  // MFMA C/D
typedef __attribute__((ext_vector_type(4))) int    intv4;    // 16B int load

__device__ __forceinline__ void wave_fence() {
    __asm__ volatile("s_waitcnt lgkmcnt(0)" ::: "memory");
}
__device__ __forceinline__ short bfbits(float f) {
    __hip_bfloat16 h = __float2bfloat16(f);
    return *reinterpret_cast<short*>(&h);
}
__device__ __forceinline__ float dot8(const float4 a0, const float4 a1,
                                      const float4 b0, const float4 b1) {
    return a0.x*b0.x + a0.y*b0.y + a0.z*b0.z + a0.w*b0.w
         + a1.x*b1.x + a1.y*b1.y + a1.z*b1.z + a1.w*b1.w;
}

// ---------------------------------------------------------------------------
// Kernel 1: precompute q/k/v tables over the 520 distinct (t, token) combos.
// tab[(t*65+tok)*32 + h*8 + d].  The faithful-bug score scale (* sqrt(C)) is
// folded into qtab.  Thread 0 also zero-inits the loss accumulator + block
// counter (replaces a separate memset dispatch; stream order guarantees this
// lands before fused_kernel starts).
// ---------------------------------------------------------------------------
__global__ void qkv_table_kernel(const float* __restrict__ tok_emb,
                                 const float* __restrict__ pos_emb,
                                 const float* __restrict__ Wq,
                                 const float* __restrict__ Wk,
                                 const float* __restrict__ Wv,
                                 float* __restrict__ qtab,
                                 float* __restrict__ ktab,
                                 float* __restrict__ vtab,
                                 float* __restrict__ loss_acc,
                                 unsigned* __restrict__ done_ctr) {
    int o = blockIdx.x * 256 + threadIdx.x;
    if (o == 0) { loss_acc[0] = 0.f; done_ctr[0] = 0u; }
    if (o >= 3 * TABSZ) return;
    int table = o / TABSZ;
    int r = o - table * TABSZ;
    int pair = r >> 5;
    int cd = r & 31;
    int t = pair / VOCAB;
    int tok = pair - t * VOCAB;
    int h = cd >> 3, d = cd & 7;
    const float* W = (table == 0) ? Wq : (table == 1) ? Wk : Wv;
    float acc = 0.f;
    #pragma unroll
    for (int c = 0; c < 32; ++c) {
        float xc = tok_emb[tok * 32 + c] + pos_emb[t * 32 + c];
        acc += xc * W[h * 256 + c * 8 + d];
    }
    if (table == 0) acc *= SQRT_C;     // faithful bug: scores * sqrt(C)
    float* tab = (table == 0) ? qtab : (table == 1) ? ktab : vtab;
    tab[r] = acc;
}

// ---------------------------------------------------------------------------
// Kernel 2: 4 independent waves per 256-block; each wave owns one batch-pair
// (16 logit rows = 4160B, exactly 65 aligned cache lines) per iteration.
//  - K/V read per-lane straight from L2-resident tables (no staging fences).
//  - MLP + logits via bf16 MFMA 16x16x32 (x2 -> x3 transpose through LDS).
//  - Logits staged in LDS, then written as wave-contiguous dwordx4 bursts:
//    every store instruction covers FULL cache lines -> no write-allocate
//    RMW. (Rounds 1-2: scattered 4B stores amplified 136MB of logits into
//    438MB write + 299MB allocate-fetch; this was the whole regression.)
//  - Loss finalized in-kernel via last-block-done atomic (no extra dispatch).
// ---------------------------------------------------------------------------
__global__ __launch_bounds__(256, 7) void fused_kernel(
        const int* __restrict__ idx, const int* __restrict__ targets,
        const float* __restrict__ qtab, const float* __restrict__ ktab,
        const float* __restrict__ vtab,
        const float* __restrict__ W_mlp,
        const float* __restrict__ b_mlp,
        const float* __restrict__ W_lm,
        const float* __restrict__ b_lm,
        float* __restrict__ out_logits,
        float* __restrict__ loss_acc,
        unsigned* __restrict__ done_ctr,
        float* __restrict__ out_loss) {
    // per-wave x3 bf16 [row][ch], row-stride 40 shorts (80B, 16B-aligned)
    __shared__ __align__(16) unsigned short sX3[4][640];
    // per-wave linear logit block: 16 rows x 65 cols fp32 (= 65 lines)
    __shared__ __align__(16) float sLog[4][1040];
    __shared__ float wsum[4];

    const int tid = threadIdx.x;
    const int w = tid >> 6, l = tid & 63;
    const int q4 = l >> 4;        // MFMA quad
    const int n  = l & 15;        // MFMA col-lane / A-row
    const int t  = l & 7, b2 = (l >> 3) & 1, h = q4;   // attention identity

    // ---- persistent B-fragments: B[k=(q4*8+j)][n] ----
    short8 wmf[2], wlf[4], wlf4;
    #pragma unroll
    for (int c = 0; c < 2; ++c)
        #pragma unroll
        for (int j = 0; j < 8; ++j)
            wmf[c][j] = bfbits(W_mlp[(q4 * 8 + j) * 32 + c * 16 + n]);
    #pragma unroll
    for (int c = 0; c < 4; ++c)
        #pragma unroll
        for (int j = 0; j < 8; ++j)
            wlf[c][j] = bfbits(W_lm[(q4 * 8 + j) * VOCAB + c * 16 + n]);
    #pragma unroll
    for (int j = 0; j < 8; ++j)
        wlf4[j] = (n == 0) ? bfbits(W_lm[(q4 * 8 + j) * VOCAB + 64]) : (short)0;
    float bmc[2], blc[4];
    #pragma unroll
    for (int c = 0; c < 2; ++c) bmc[c] = b_mlp[c * 16 + n];
    #pragma unroll
    for (int c = 0; c < 4; ++c) blc[c] = b_lm[c * 16 + n];
    const float bl64 = b_lm[64];
    const float4v zf = {0.f, 0.f, 0.f, 0.f};

    float loss_local = 0.f;

    for (int pb = blockIdx.x * 4 + w; pb < PAIRS; pb += NWAVES) {
        const int rbase = pb * 16;

        // ---- tokens / targets: per-lane vector loads (wave-broadcast lines)
        const intv4 ta = *((const intv4*)(idx + rbase + b2 * 8));
        const intv4 tb = *((const intv4*)(idx + rbase + b2 * 8) + 1);
        const int tok_t = idx[rbase + b2 * 8 + t];          // own q token
        const intv4 tg = *((const intv4*)(targets + rbase + q4 * 4));

        // ---- q row (already * sqrt(C)) ----
        const float* qp = qtab + (t * VOCAB + tok_t) * 32 + h * 8;
        const float4 q0 = *(const float4*)(qp);
        const float4 q1 = *(const float4*)(qp + 4);

        const int toks[8] = {ta[0], ta[1], ta[2], ta[3],
                             tb[0], tb[1], tb[2], tb[3]};

        // ---- scores: per-lane K reads (8 distinct addrs per instruction) --
        float sc[8], m = -1e30f;
        #pragma unroll
        for (int s = 0; s < 8; ++s) {
            const float* kp = ktab + (s * VOCAB + toks[s]) * 32 + h * 8;
            float4 k0 = *(const float4*)(kp);
            float4 k1 = *(const float4*)(kp + 4);
            float d = dot8(q0, q1, k0, k1);
            sc[s] = d;
            if (s <= t) m = fmaxf(m, d);
        }
        float p[8], sum = 0.f;
        #pragma unroll
        for (int s = 0; s < 8; ++s) {
            p[s] = (s <= t) ? __expf(sc[s] - m) : 0.f;
            sum += p[s];
        }
        float inv = 1.f / sum;

        // ---- V accumulation ----
        float o[8];
        #pragma unroll
        for (int d = 0; d < 8; ++d) o[d] = 0.f;
        #pragma unroll
        for (int s = 0; s < 8; ++s) {
            const float* vp = vtab + (s * VOCAB + toks[s]) * 32 + h * 8;
            float4 v0 = *(const float4*)(vp);
            float4 v1 = *(const float4*)(vp + 4);
            o[0] += p[s] * v0.x; o[1] += p[s] * v0.y;
            o[2] += p[s] * v0.z; o[3] += p[s] * v0.w;
            o[4] += p[s] * v1.x; o[5] += p[s] * v1.y;
            o[6] += p[s] * v1.z; o[7] += p[s] * v1.w;
        }
        short8 a2;
        #pragma unroll
        for (int d = 0; d < 8; ++d) a2[d] = bfbits(o[d] * inv);

        // ---- MLP: x3 = relu(x2 @ W_mlp + b), 2 MFMAs ----
        float4v d0 = __builtin_amdgcn_mfma_f32_16x16x32_bf16(a2, wmf[0], zf, 0, 0, 0);
        float4v d1 = __builtin_amdgcn_mfma_f32_16x16x32_bf16(a2, wmf[1], zf, 0, 0, 0);
        #pragma unroll
        for (int i = 0; i < 4; ++i) {
            int row = q4 * 4 + i;
            sX3[w][row * 40 + n]      = (unsigned short)bfbits(fmaxf(d0[i] + bmc[0], 0.f));
            sX3[w][row * 40 + 16 + n] = (unsigned short)bfbits(fmaxf(d1[i] + bmc[1], 0.f));
        }
        wave_fence();
        // C->A transpose via LDS: one b128 read
        short8 a3 = *(const short8*)(&sX3[w][n * 40 + q4 * 8]);

        // ---- logits: 5 MFMAs (cols 0..63 + padded col-64 fragment) ----
        float4v Lc[4];
        #pragma unroll
        for (int c = 0; c < 4; ++c)
            Lc[c] = __builtin_amdgcn_mfma_f32_16x16x32_bf16(a3, wlf[c], zf, 0, 0, 0);
        float4v L64 = __builtin_amdgcn_mfma_f32_16x16x32_bf16(a3, wlf4, zf, 0, 0, 0);

        // ---- bias + LDS stage + sum-exp + inline target pick ----
        float part[4] = {0.f, 0.f, 0.f, 0.f};
        #pragma unroll
        for (int c = 0; c < 4; ++c) {
            #pragma unroll
            for (int i = 0; i < 4; ++i) {
                float Lv = Lc[c][i] + blc[c];
                sLog[w][(q4 * 4 + i) * 65 + c * 16 + n] = Lv;
                part[i] += __expf(Lv);
                if (c * 16 + n == tg[i]) loss_local -= Lv;   // exactly 1 lane/row
            }
        }
        if (n == 0) {
            #pragma unroll
            for (int i = 0; i < 4; ++i) {
                float Lv = L64[i] + bl64;
                sLog[w][(q4 * 4 + i) * 65 + 64] = Lv;
                part[i] += __expf(Lv);
                if (tg[i] == 64) loss_local -= Lv;
            }
        }
        wave_fence();

        // ---- full-line burst store: 4x wave-wide 1KB + one 64B tail ----
        {
            const float4* src = (const float4*)(&sLog[w][0]);
            float4* dst = (float4*)(out_logits + (size_t)pb * 1040);
            #pragma unroll
            for (int k = 0; k < 4; ++k)
                dst[k * 64 + l] = src[k * 64 + l];
            if (l < 4) dst[256 + l] = src[256 + l];
        }

        #pragma unroll
        for (int off = 1; off < 16; off <<= 1) {
            #pragma unroll
            for (int i = 0; i < 4; ++i) part[i] += __shfl_xor(part[i], off);
        }
        if (n == 0)
            loss_local += __logf(part[0]) + __logf(part[1])
                        + __logf(part[2]) + __logf(part[3]);
    }

    #pragma unroll
    for (int off = 1; off < 64; off <<= 1) loss_local += __shfl_xor(loss_local, off);
    if (l == 0) wsum[w] = loss_local;
    __syncthreads();
    if (tid == 0) {
        atomicAdd(loss_acc, wsum[0] + wsum[1] + wsum[2] + wsum[3]);
        __threadfence();
        unsigned done = atomicAdd(done_ctr, 1u);
        if (done == NBLOCKS - 1) {
            __threadfence();
            float tot = atomicAdd(loss_acc, 0.f);   // coherent read
            out_loss[0] = tot * (1.f / (float)ROWS);
        }
    }
}

extern "C" void kernel_launch(void* const* d_in, const int* in_sizes, int n_in,
                              void* d_out, int out_size, void* d_ws, size_t ws_size,
                              hipStream_t stream) {
    const int* idx        = (const int*)d_in[0];
    const int* targets    = (const int*)d_in[1];
    const float* tok_emb  = (const float*)d_in[2];
    const float* pos_emb  = (const float*)d_in[3];
    const float* Wq       = (const float*)d_in[4];
    const float* Wk       = (const float*)d_in[5];
    const float* Wv       = (const float*)d_in[6];
    const float* W_mlp    = (const float*)d_in[7];
    const float* b_mlp    = (const float*)d_in[8];
    const float* W_lm     = (const float*)d_in[9];
    const float* b_lm     = (const float*)d_in[10];
    float* out            = (float*)d_out;

    float* ws        = (float*)d_ws;
    float* loss_ptr  = ws;
    unsigned* ctr    = (unsigned*)(ws + 1);
    float* qtab      = ws + 16;
    float* ktab      = qtab + TABSZ;
    float* vtab      = ktab + TABSZ;
    float* out_loss  = out + (size_t)ROWS * VOCAB;

    qkv_table_kernel<<<(3 * TABSZ + 255) / 256, 256, 0, stream>>>(
        tok_emb, pos_emb, Wq, Wk, Wv, qtab, ktab, vtab, loss_ptr, ctr);

    fused_kernel<<<NBLOCKS, 256, 0, stream>>>(
        idx, targets, qtab, ktab, vtab, W_mlp, b_mlp, W_lm, b_lm,
        out, loss_ptr, ctr, out_loss);
}

// Round 4
// 350.277 us; speedup vs baseline: 1.3650x; 1.3213x over previous
//
#include <hip/hip_runtime.h>
#include <hip/hip_bf16.h>

#define VOCAB   65
#define SQRT_C  5.656854249492381f
#define BATCHES 65536
#define ROWS    (BATCHES * 8)
#define TABSZ   (8 * VOCAB * 32)       // 16640 floats per q/k/v table
#define PAIRS   (BATCHES / 2)          // 32768 batch-pairs (16 rows each)
#define NBLOCKS 2048
#define NWAVES  (NBLOCKS * 4)

typedef __attribute__((ext_vector_type(8))) short  short8;   // 8 bf16 = 4 VGPRs
typedef __attribute__((ext_vector_type(4))) float  float4v;  // MFMA C/D

__device__ __forceinline__ void wave_fence() {
    __asm__ volatile("s_waitcnt lgkmcnt(0)" ::: "memory");
}
__device__ __forceinline__ short bfbits(float f) {
    __hip_bfloat16 h = __float2bfloat16(f);
    return *reinterpret_cast<short*>(&h);
}

// ---------------------------------------------------------------------------
// Kernel 1: precompute q/k/v tables over the 520 distinct (t, token) combos.
// tab[(t*65+tok)*32 + h*8 + d].  Score scale (* sqrt(C), faithful bug) folded
// into qtab.  Thread 0 zero-inits the loss accumulator + done counter.
// ---------------------------------------------------------------------------
__global__ void qkv_table_kernel(const float* __restrict__ tok_emb,
                                 const float* __restrict__ pos_emb,
                                 const float* __restrict__ Wq,
                                 const float* __restrict__ Wk,
                                 const float* __restrict__ Wv,
                                 float* __restrict__ qtab,
                                 float* __restrict__ ktab,
                                 float* __restrict__ vtab,
                                 float* __restrict__ loss_acc,
                                 unsigned* __restrict__ done_ctr) {
    int o = blockIdx.x * 256 + threadIdx.x;
    if (o == 0) { loss_acc[0] = 0.f; done_ctr[0] = 0u; }
    if (o >= 3 * TABSZ) return;
    int table = o / TABSZ;
    int r = o - table * TABSZ;
    int pair = r >> 5;
    int cd = r & 31;
    int t = pair / VOCAB;
    int tok = pair - t * VOCAB;
    int h = cd >> 3, d = cd & 7;
    const float* W = (table == 0) ? Wq : (table == 1) ? Wk : Wv;
    float acc = 0.f;
    #pragma unroll
    for (int c = 0; c < 32; ++c) {
        float xc = tok_emb[tok * 32 + c] + pos_emb[t * 32 + c];
        acc += xc * W[h * 256 + c * 8 + d];
    }
    if (table == 0) acc *= SQRT_C;     // faithful bug: scores * sqrt(C)
    float* tab = (table == 0) ? qtab : (table == 1) ? ktab : vtab;
    tab[r] = acc;
}

// Register-prefetch of one iteration's K/V/q gather (addresses from TOKV).
// Lane mapping identical to the round-0 LDS gather; destinations are regs.
#define GATHER(TOKV)                                                         \
  { int c1 = l + 64;                                                         \
    int s0_ = (l >> 1) & 7,  g0 = l >> 4,  d20 = l & 1;                      \
    int s1_ = (c1 >> 1) & 7, g1 = c1 >> 4, d21 = c1 & 1;                     \
    int ts0 = __shfl((TOKV), (g0 & 1) * 8 + s0_);                            \
    int ts1 = __shfl((TOKV), (g1 & 1) * 8 + s1_);                            \
    int ga0 = (s0_ * VOCAB + ts0) * 32 + (g0 >> 1) * 8 + d20 * 4;            \
    int ga1 = (s1_ * VOCAB + ts1) * 32 + (g1 >> 1) * 8 + d21 * 4;            \
    kr0 = *(const float4*)(ktab + ga0); kr1 = *(const float4*)(ktab + ga1);  \
    vr0 = *(const float4*)(vtab + ga0); vr1 = *(const float4*)(vtab + ga1);  \
    int tt = __shfl((TOKV), b2 * 8 + t);                                     \
    const float* qp_ = qtab + (t * VOCAB + tt) * 32 + h * 8;                 \
    qf0 = *(const float4*)(qp_); qf1 = *(const float4*)(qp_ + 4); }

// ---------------------------------------------------------------------------
// Kernel 2: 4 independent waves per 256-block; each wave owns one batch-pair
// (16 logit rows) per iteration, 4 iterations per wave.
//  - Round-0 memory structure (measured clean: FETCH 3MB / WRITE 133MB):
//    K/V staged via LDS, scattered register logit stores.  Rounds 1-3's
//    per-lane direct table gathers blew traffic to 760MB regardless of
//    store pattern -- load structure was the culprit.
//  - NEW: software pipeline.  Next iteration's idx/targets/K/V/q loads are
//    issued into registers under the current iteration's attention + MFMA +
//    epilogue; LDS ds_writes happen at the loop top (single buffer is safe:
//    a wave's iterations are sequential).
//  - Inline target-logit extraction (no b6 gather/MFMA), sqrt(C) folded
//    into qtab, loss finalized in-kernel (2 dispatches total).
// ---------------------------------------------------------------------------
__global__ __launch_bounds__(256) void fused_kernel(
        const int* __restrict__ idx, const int* __restrict__ targets,
        const float* __restrict__ qtab, const float* __restrict__ ktab,
        const float* __restrict__ vtab,
        const float* __restrict__ W_mlp,
        const float* __restrict__ b_mlp,
        const float* __restrict__ W_lm,
        const float* __restrict__ b_lm,
        float* __restrict__ out_logits,
        float* __restrict__ loss_acc,
        unsigned* __restrict__ done_ctr,
        float* __restrict__ out_loss) {
    // per-wave K/V: [grp=h*2+b2][s][d], grp-stride 68 words (conflict-free
    // 8-group broadcast: 68%32=4 -> groups start 4 banks apart)
    __shared__ __align__(16) float sK[4][544];
    __shared__ __align__(16) float sV[4][544];
    // per-wave x3 bf16 [row][ch], row-stride 40 shorts (80B, 16B-aligned)
    __shared__ __align__(16) unsigned short sX3[4][640];
    __shared__ float wsum[4];

    const int tid = threadIdx.x;
    const int w = tid >> 6, l = tid & 63;
    const int q4 = l >> 4;        // MFMA quad
    const int n  = l & 15;        // MFMA col-lane / A-row
    const int t  = l & 7, b2 = (l >> 3) & 1, h = q4;   // attention identity

    // lane-static LDS gather destinations (floats)
    const int la0 = (l >> 4) * 68 + ((l >> 1) & 7) * 8 + (l & 1) * 4;
    const int la1 = ((l + 64) >> 4) * 68 + ((l >> 1) & 7) * 8 + (l & 1) * 4;

    // ---- persistent B-fragments: B[k=(q4*8+j)][n] ----
    short8 wmf[2], wlf[4], wlf4;
    #pragma unroll
    for (int c = 0; c < 2; ++c)
        #pragma unroll
        for (int j = 0; j < 8; ++j)
            wmf[c][j] = bfbits(W_mlp[(q4 * 8 + j) * 32 + c * 16 + n]);
    #pragma unroll
    for (int c = 0; c < 4; ++c)
        #pragma unroll
        for (int j = 0; j < 8; ++j)
            wlf[c][j] = bfbits(W_lm[(q4 * 8 + j) * VOCAB + c * 16 + n]);
    #pragma unroll
    for (int j = 0; j < 8; ++j)
        wlf4[j] = (n == 0) ? bfbits(W_lm[(q4 * 8 + j) * VOCAB + 64]) : (short)0;
    float bmc[2], blc[4];
    #pragma unroll
    for (int c = 0; c < 2; ++c) bmc[c] = b_mlp[c * 16 + n];
    #pragma unroll
    for (int c = 0; c < 4; ++c) blc[c] = b_lm[c * 16 + n];
    const float bl64 = b_lm[64];
    const float4v zf = {0.f, 0.f, 0.f, 0.f};

    float loss_local = 0.f;

    // ---- pipeline prologue: load iteration 0's inputs into registers ----
    int pb = blockIdx.x * 4 + w;
    int tokv = 0, tgv = 0;
    if (l < 16) { tokv = idx[pb * 16 + l]; tgv = targets[pb * 16 + l]; }
    float4 kr0, kr1, vr0, vr1, qf0, qf1;
    GATHER(tokv)

    for (; pb < PAIRS; pb += NWAVES) {
        // ---- stage prefetched K/V into LDS ----
        *(float4*)(&sK[w][la0]) = kr0;  *(float4*)(&sK[w][la1]) = kr1;
        *(float4*)(&sV[w][la0]) = vr0;  *(float4*)(&sV[w][la1]) = vr1;
        wave_fence();

        // ---- issue next iteration's idx/targets loads (hidden under attn)
        const int pbn = pb + NWAVES;
        int tokv_n = 0, tgv_n = 0;
        if (pbn < PAIRS && l < 16) {
            tokv_n = idx[pbn * 16 + l];
            tgv_n  = targets[pbn * 16 + l];
        }
        // current targets for my 4 rows
        int tgrc[4];
        #pragma unroll
        for (int i = 0; i < 4; ++i) tgrc[i] = __shfl(tgv, q4 * 4 + i);

        // ---- attention (fp32): lane (b2,h,t); out lands in MFMA A-layout --
        const float* kb = &sK[w][(h * 2 + b2) * 68];
        const float* vb = &sV[w][(h * 2 + b2) * 68];
        float sc[8], m = -1e30f;
        #pragma unroll
        for (int s = 0; s < 8; ++s) {
            float4 k0 = *(const float4*)(kb + s * 8);
            float4 k1 = *(const float4*)(kb + s * 8 + 4);
            float d = qf0.x * k0.x + qf0.y * k0.y + qf0.z * k0.z + qf0.w * k0.w
                    + qf1.x * k1.x + qf1.y * k1.y + qf1.z * k1.z + qf1.w * k1.w;
            sc[s] = d;                   // qtab already carries * sqrt(C)
            if (s <= t) m = fmaxf(m, d);
        }
        float p[8], sum = 0.f;
        #pragma unroll
        for (int s = 0; s < 8; ++s) {
            p[s] = (s <= t) ? __expf(sc[s] - m) : 0.f;
            sum += p[s];
        }
        float inv = 1.f / sum;
        float o[8];
        #pragma unroll
        for (int d = 0; d < 8; ++d) o[d] = 0.f;
        #pragma unroll
        for (int s = 0; s < 8; ++s) {
            float4 v0 = *(const float4*)(vb + s * 8);
            float4 v1 = *(const float4*)(vb + s * 8 + 4);
            o[0] += p[s] * v0.x; o[1] += p[s] * v0.y;
            o[2] += p[s] * v0.z; o[3] += p[s] * v0.w;
            o[4] += p[s] * v1.x; o[5] += p[s] * v1.y;
            o[6] += p[s] * v1.z; o[7] += p[s] * v1.w;
        }
        short8 a2;
        #pragma unroll
        for (int d = 0; d < 8; ++d) a2[d] = bfbits(o[d] * inv);

        // ---- prefetch next iteration's K/V/q into registers (qf/kr/vr dead)
        if (pbn < PAIRS) { GATHER(tokv_n) }

        // ---- MLP: x3 = relu(x2 @ W_mlp + b), 2 MFMAs ----
        float4v d0 = __builtin_amdgcn_mfma_f32_16x16x32_bf16(a2, wmf[0], zf, 0, 0, 0);
        float4v d1 = __builtin_amdgcn_mfma_f32_16x16x32_bf16(a2, wmf[1], zf, 0, 0, 0);
        #pragma unroll
        for (int i = 0; i < 4; ++i) {
            int row = q4 * 4 + i;
            sX3[w][row * 40 + n]      = (unsigned short)bfbits(fmaxf(d0[i] + bmc[0], 0.f));
            sX3[w][row * 40 + 16 + n] = (unsigned short)bfbits(fmaxf(d1[i] + bmc[1], 0.f));
        }
        wave_fence();
        // C->A transpose via LDS: one b128 read
        short8 a3 = *(const short8*)(&sX3[w][n * 40 + q4 * 8]);

        // ---- logits: 5 MFMAs (cols 0..63 + padded col-64 fragment) ----
        float4v Lc[4];
        #pragma unroll
        for (int c = 0; c < 4; ++c)
            Lc[c] = __builtin_amdgcn_mfma_f32_16x16x32_bf16(a3, wlf[c], zf, 0, 0, 0);
        float4v L64 = __builtin_amdgcn_mfma_f32_16x16x32_bf16(a3, wlf4, zf, 0, 0, 0);

        // ---- bias + scattered store + sum-exp + inline target pick ----
        size_t rb = (size_t)pb * 16;
        float part[4] = {0.f, 0.f, 0.f, 0.f};
        #pragma unroll
        for (int c = 0; c < 4; ++c) {
            #pragma unroll
            for (int i = 0; i < 4; ++i) {
                float Lv = Lc[c][i] + blc[c];
                out_logits[(rb + q4 * 4 + i) * VOCAB + c * 16 + n] = Lv;
                part[i] += __expf(Lv);
                if (c * 16 + n == tgrc[i]) loss_local -= Lv;  // 1 lane/row
            }
        }
        if (n == 0) {
            #pragma unroll
            for (int i = 0; i < 4; ++i) {
                float Lv = L64[i] + bl64;
                out_logits[(rb + q4 * 4 + i) * VOCAB + 64] = Lv;
                part[i] += __expf(Lv);
                if (tgrc[i] == 64) loss_local -= Lv;
            }
        }
        #pragma unroll
        for (int off = 1; off < 16; off <<= 1) {
            #pragma unroll
            for (int i = 0; i < 4; ++i) part[i] += __shfl_xor(part[i], off);
        }
        if (n == 0)
            loss_local += __logf(part[0]) + __logf(part[1])
                        + __logf(part[2]) + __logf(part[3]);

        // rotate pipeline state
        tokv = tokv_n; tgv = tgv_n;
    }

    #pragma unroll
    for (int off = 1; off < 64; off <<= 1) loss_local += __shfl_xor(loss_local, off);
    if (l == 0) wsum[w] = loss_local;
    __syncthreads();
    if (tid == 0) {
        atomicAdd(loss_acc, wsum[0] + wsum[1] + wsum[2] + wsum[3]);
        __threadfence();
        unsigned done = atomicAdd(done_ctr, 1u);
        if (done == NBLOCKS - 1) {
            __threadfence();
            float tot = atomicAdd(loss_acc, 0.f);   // coherent read
            out_loss[0] = tot * (1.f / (float)ROWS);
        }
    }
}

extern "C" void kernel_launch(void* const* d_in, const int* in_sizes, int n_in,
                              void* d_out, int out_size, void* d_ws, size_t ws_size,
                              hipStream_t stream) {
    const int* idx        = (const int*)d_in[0];
    const int* targets    = (const int*)d_in[1];
    const float* tok_emb  = (const float*)d_in[2];
    const float* pos_emb  = (const float*)d_in[3];
    const float* Wq       = (const float*)d_in[4];
    const float* Wk       = (const float*)d_in[5];
    const float* Wv       = (const float*)d_in[6];
    const float* W_mlp    = (const float*)d_in[7];
    const float* b_mlp    = (const float*)d_in[8];
    const float* W_lm     = (const float*)d_in[9];
    const float* b_lm     = (const float*)d_in[10];
    float* out            = (float*)d_out;

    float* ws        = (float*)d_ws;
    float* loss_ptr  = ws;
    unsigned* ctr    = (unsigned*)(ws + 1);
    float* qtab      = ws + 16;
    float* ktab      = qtab + TABSZ;
    float* vtab      = ktab + TABSZ;
    float* out_loss  = out + (size_t)ROWS * VOCAB;

    qkv_table_kernel<<<(3 * TABSZ + 255) / 256, 256, 0, stream>>>(
        tok_emb, pos_emb, Wq, Wk, Wv, qtab, ktab, vtab, loss_ptr, ctr);

    fused_kernel<<<NBLOCKS, 256, 0, stream>>>(
        idx, targets, qtab, ktab, vtab, W_mlp, b_mlp, W_lm, b_lm,
        out, loss_ptr, ctr, out_loss);
}